// Round 1
// baseline (1018.124 us; speedup 1.0000x reference)
//
#include <hip/hip_runtime.h>
#include <hip/hip_bf16.h>

#define T_STEPS 512
#define B_SZ 64
#define H_SZ 96
#define I_SZ 2048

// ---------------- GEMM: xproj0 = x @ w_ih0^T + b_ih0 ----------------
// M = B*T = 32768, K = 2048, N = 96. Block tile: 64(M) x 96(N) x 32(K).
// 256 threads, per-thread 4 rows x 6 cols.
#define BM 64
#define BN 96
#define BK 32

__global__ __launch_bounds__(256) void xproj_gemm(
    const float* __restrict__ x,    // [32768, 2048]
    const float* __restrict__ w,    // [96, 2048]
    const float* __restrict__ bias, // [96]
    float* __restrict__ out)        // [32768, 96]
{
    __shared__ float xs[BK][BM + 4]; // [k][m], row stride 68 floats (16B aligned)
    __shared__ float ws[BK][BN + 4]; // [k][j], row stride 100 floats

    const int tid = threadIdx.x;
    const int m0 = blockIdx.x * BM;
    const int tm = tid & 15;   // row group 0..15 -> 4 rows each
    const int tn = tid >> 4;   // col group 0..15 -> 6 cols each

    float acc[4][6];
#pragma unroll
    for (int r = 0; r < 4; ++r)
#pragma unroll
        for (int c = 0; c < 6; ++c) acc[r][c] = 0.f;

    for (int k0 = 0; k0 < I_SZ; k0 += BK) {
        // stage x tile: 64 rows x 32 k = 512 float4 loads
#pragma unroll
        for (int it = 0; it < 2; ++it) {
            int L = tid + it * 256;          // 0..511
            int m = L >> 3;                  // 0..63
            int k4 = (L & 7) * 4;            // 0,4,...,28
            float4 v = *(const float4*)&x[(size_t)(m0 + m) * I_SZ + k0 + k4];
            xs[k4 + 0][m] = v.x; xs[k4 + 1][m] = v.y;
            xs[k4 + 2][m] = v.z; xs[k4 + 3][m] = v.w;
        }
        // stage w tile: 96 rows x 32 k = 768 float4 loads
#pragma unroll
        for (int it = 0; it < 3; ++it) {
            int L = tid + it * 256;          // 0..767
            int j = L >> 3;                  // 0..95
            int k4 = (L & 7) * 4;
            float4 v = *(const float4*)&w[(size_t)j * I_SZ + k0 + k4];
            ws[k4 + 0][j] = v.x; ws[k4 + 1][j] = v.y;
            ws[k4 + 2][j] = v.z; ws[k4 + 3][j] = v.w;
        }
        __syncthreads();

#pragma unroll
        for (int k = 0; k < BK; ++k) {
            float a[4], b[6];
#pragma unroll
            for (int r = 0; r < 4; ++r) a[r] = xs[k][tm * 4 + r];
#pragma unroll
            for (int c = 0; c < 6; ++c) b[c] = ws[k][tn * 6 + c];
#pragma unroll
            for (int r = 0; r < 4; ++r)
#pragma unroll
                for (int c = 0; c < 6; ++c) acc[r][c] += a[r] * b[c];
        }
        __syncthreads();
    }

#pragma unroll
    for (int r = 0; r < 4; ++r) {
        int m = m0 + tm * 4 + r;
#pragma unroll
        for (int c = 0; c < 6; ++c) {
            int j = tn * 6 + c;
            out[(size_t)m * H_SZ + j] = acc[r][c] + bias[j];
        }
    }
}

// ---------------- Fused 3-layer pipelined recurrence + FC head ----------------
// 64 blocks (one per batch element), 512 threads.
// Thread groups (96 threads each):
//   g0 [0,96)   : layer0 w_hh0 dot vs h0 ; also combines layer0 (has xproj row)
//   g1 [96,192) : layer1 w_ih1 dot vs h0 ; combines layer1 (needs p1b from LDS)
//   g2 [192,288): layer1 w_hh1 dot vs h1 ; writes p1b
//   g3 [288,384): layer2 w_ih2 dot vs h1 ; combines layer2 (needs p2b)
//   g4 [384,480): layer2 w_hh2 dot vs h2 ; writes p2b
// Wavefront schedule: at tick i, layer0 produces h0[i], layer1 h1[i-1], layer2 h2[i-2].

__device__ __forceinline__ float fast_tanh(float x) {
    float cx = fminf(fmaxf(x, -15.f), 15.f);
    float e = __expf(2.f * cx);
    return 1.f - 2.f / (e + 1.f);
}

__global__ __launch_bounds__(512) void rnn3_fused(
    const float* __restrict__ xproj0, // [B*T, 96], includes b_ih0
    const float* __restrict__ w_hh0, const float* __restrict__ b_hh0,
    const float* __restrict__ w_ih1, const float* __restrict__ b_ih1,
    const float* __restrict__ w_hh1, const float* __restrict__ b_hh1,
    const float* __restrict__ w_ih2, const float* __restrict__ b_ih2,
    const float* __restrict__ w_hh2, const float* __restrict__ b_hh2,
    const float* __restrict__ fc_w, const float* __restrict__ fc_b,
    float* __restrict__ out)          // [B]
{
    __shared__ __align__(16) float h0[H_SZ];
    __shared__ __align__(16) float h1[H_SZ];
    __shared__ __align__(16) float h2[H_SZ];
    __shared__ float p1b[H_SZ];
    __shared__ float p2b[H_SZ];
    __shared__ float red[H_SZ];

    const int t = threadIdx.x;
    const int b = blockIdx.x;
    const int g = t / H_SZ;          // 0..5
    const int j = t - g * H_SZ;
    const bool active = (t < 5 * H_SZ);

    // per-thread weight row in VGPRs
    float wreg[H_SZ];
    if (active) {
        const float* wp;
        switch (g) {
            case 0: wp = w_hh0; break;
            case 1: wp = w_ih1; break;
            case 2: wp = w_hh1; break;
            case 3: wp = w_ih2; break;
            default: wp = w_hh2; break;
        }
        const float* wrow = wp + j * H_SZ;
#pragma unroll
        for (int k = 0; k < H_SZ; k += 4) {
            float4 v = *(const float4*)&wrow[k];
            wreg[k] = v.x; wreg[k + 1] = v.y; wreg[k + 2] = v.z; wreg[k + 3] = v.w;
        }
    }

    // bias for combine threads
    float cbias = 0.f;
    if (t < 96)                  cbias = b_hh0[t];
    else if (t < 192)            cbias = b_ih1[t - 96] + b_hh1[t - 96];
    else if (t >= 288 && t < 384) cbias = b_ih2[t - 288] + b_hh2[t - 288];

    if (t < H_SZ) { h0[t] = 0.f; h1[t] = 0.f; h2[t] = 0.f; }
    __syncthreads();

    const float* xp_base = xproj0 + (size_t)b * T_STEPS * H_SZ;
    float xp_cur = (t < 96) ? xp_base[t] : 0.f;   // row for tick 0

    for (int i = 0; i < T_STEPS + 2; ++i) {
        // prefetch next tick's xproj row (hidden behind the dot)
        float xp_next = 0.f;
        if (t < 96) {
            int ii = (i + 1 < T_STEPS) ? (i + 1) : (T_STEPS - 1);
            xp_next = xp_base[(size_t)ii * H_SZ + t];
        }

        float part = 0.f;
        if (active) {
            const float* hs = (g <= 1) ? h0 : (g <= 3) ? h1 : h2;
            float a0 = 0.f, a1 = 0.f, a2 = 0.f, a3 = 0.f;
#pragma unroll
            for (int k = 0; k < H_SZ; k += 4) {
                float4 hv = *(const float4*)&hs[k];
                a0 += wreg[k]     * hv.x;
                a1 += wreg[k + 1] * hv.y;
                a2 += wreg[k + 2] * hv.z;
                a3 += wreg[k + 3] * hv.w;
            }
            part = (a0 + a1) + (a2 + a3);
            if (g == 2) p1b[j] = part;
            else if (g == 4) p2b[j] = part;
        }
        __syncthreads();

        // combine + state update
        if (t < 96) {                       // layer0 -> h0[i]
            if (i < T_STEPS) h0[j] = fast_tanh(xp_cur + part + cbias);
        } else if (t < 192) {               // layer1 -> h1[i-1]
            if (i >= 1 && i <= T_STEPS) h1[j] = fast_tanh(part + p1b[j] + cbias);
        } else if (t >= 288 && t < 384) {   // layer2 -> h2[i-2]
            if (i >= 2) h2[j] = fast_tanh(part + p2b[j] + cbias);
        }
        __syncthreads();

        xp_cur = xp_next;
    }

    // FC head: out[b] = sum_j h2[j]*fc_w[j] + fc_b
    if (t < H_SZ) red[t] = h2[t] * fc_w[t];
    __syncthreads();
    if (t == 0) {
        float s = 0.f;
#pragma unroll
        for (int k = 0; k < H_SZ; ++k) s += red[k];
        out[b] = s + fc_b[0];
    }
}

// ---------------- launcher ----------------
extern "C" void kernel_launch(void* const* d_in, const int* in_sizes, int n_in,
                              void* d_out, int out_size, void* d_ws, size_t ws_size,
                              hipStream_t stream) {
    const float* x     = (const float*)d_in[0];
    const float* w_ih0 = (const float*)d_in[1];
    const float* w_hh0 = (const float*)d_in[2];
    const float* b_ih0 = (const float*)d_in[3];
    const float* b_hh0 = (const float*)d_in[4];
    const float* w_ih1 = (const float*)d_in[5];
    const float* w_hh1 = (const float*)d_in[6];
    const float* b_ih1 = (const float*)d_in[7];
    const float* b_hh1 = (const float*)d_in[8];
    const float* w_ih2 = (const float*)d_in[9];
    const float* w_hh2 = (const float*)d_in[10];
    const float* b_ih2 = (const float*)d_in[11];
    const float* b_hh2 = (const float*)d_in[12];
    const float* fc_w  = (const float*)d_in[13];
    const float* fc_b  = (const float*)d_in[14];

    float* xproj = (float*)d_ws;  // 32768 * 96 floats = 12.6 MB

    const int M = B_SZ * T_STEPS; // 32768
    xproj_gemm<<<M / BM, 256, 0, stream>>>(x, w_ih0, b_ih0, xproj);
    rnn3_fused<<<B_SZ, 512, 0, stream>>>(xproj,
                                         w_hh0, b_hh0,
                                         w_ih1, b_ih1, w_hh1, b_hh1,
                                         w_ih2, b_ih2, w_hh2, b_hh2,
                                         fc_w, fc_b, (float*)d_out);
}